// Round 10
// baseline (229.142 us; speedup 1.0000x reference)
//
#include <hip/hip_runtime.h>

#define N_NODES 50000
#define N_EDGES 800000
#define D 128
#define NBUK 196     // buckets of 256 nodes (dst>>8)
#define HB 128       // histogram/staging blocks
#define EPB 6250     // edges per block: 128*6250 = 800000 exactly

typedef __attribute__((ext_vector_type(8))) short bf16x8;
typedef __attribute__((ext_vector_type(4))) float f32x4;

__device__ inline unsigned short f2bf(float f) {
    unsigned u = __float_as_uint(f);
    u += 0x7fffu + ((u >> 16) & 1u);   // round-to-nearest-even
    return (unsigned short)(u >> 16);
}
__device__ inline float bf2f(unsigned short h) {
    return __uint_as_float((unsigned)h << 16);
}

// ---------------- merged: W prep (blocks 0..127) + bucket histogram (blocks 128..255) ----
__global__ __launch_bounds__(256) void prep_hist_kernel(const float* __restrict__ W1,
                                                        const float* __restrict__ W2,
                                                        unsigned short* __restrict__ Wt,
                                                        const int* __restrict__ dst,
                                                        int* __restrict__ H) {
    __shared__ int hist[NBUK];
    const int b = blockIdx.x;
    const int t = threadIdx.x;
    if (b < 128) {
        // W prep: transpose + split-bf16 + XOR swizzle
        int tid = b * 256 + t;          // 0..32767
        int a = tid >> 14;
        int idx = tid & 16383;
        const float* W = a ? W2 : W1;
        float w = W[idx];
        unsigned short hi = f2bf(w);
        unsigned short lo = f2bf(w - bf2f(hi));
        int k = idx >> 7, col = idx & 127;
        int byte = (col * 128 + k) * 2;
        int swz = byte ^ (((byte >> 8) & 7) << 4);
        unsigned short* base = Wt + a * 32768;
        *(unsigned short*)((char*)base + swz) = hi;
        *(unsigned short*)((char*)(base + 16384) + swz) = lo;
    } else {
        // per-block bucket histogram (no global atomics)
        const int blk = b - 128;
        if (t < NBUK) hist[t] = 0;
        __syncthreads();
        const int e0 = blk * EPB;
        for (int i = t; i < EPB; i += 256)
            atomicAdd(&hist[dst[e0 + i] >> 8], 1);
        __syncthreads();
        if (t < NBUK) H[blk * NBUK + t] = hist[t];
    }
}

// ---------------- stage: self-computed bases + scatter into block-exclusive ranges -----
__global__ __launch_bounds__(256) void kstage_kernel(const int* __restrict__ src,
                                                     const int* __restrict__ dst,
                                                     const int* __restrict__ H,
                                                     unsigned* __restrict__ stage) {
    __shared__ int cur[256];
    __shared__ int sarr[256];
    const int t = threadIdx.x;
    const int myb = blockIdx.x;
    // column sums + my-block prefix from H (L2-hot, 100 KB)
    int tot = 0, pre = 0;
    if (t < NBUK) {
        for (int b = 0; b < HB; ++b) {
            int h = H[b * NBUK + t];
            tot += h;
            if (b < myb) pre += h;
        }
    }
    sarr[t] = (t < NBUK) ? tot : 0;
    __syncthreads();
    #pragma unroll
    for (int off = 1; off < 256; off <<= 1) {
        int add = (t >= off) ? sarr[t - off] : 0;
        __syncthreads();
        sarr[t] += add;
        __syncthreads();
    }
    if (t < NBUK) cur[t] = (sarr[t] - tot) + pre;   // bucket base + my prefix
    __syncthreads();
    const int e0 = myb * EPB;
    for (int i = t; i < EPB; i += 256) {
        int d = dst[e0 + i];
        int s = src[e0 + i];
        int pos = atomicAdd(&cur[d >> 8], 1);
        stage[pos] = (unsigned)s | ((unsigned)(d & 255) << 16);
    }
}

// ---------------- merged: gemm1 (blocks 0..781) + kfinal (blocks 782..977) -------------
// gemm: Cb[row][col] (bf16) = A[row][:] @ W  via split-bf16 MFMA (3 mfma/tile)
// kfinal: self-computed bucket base/size from H; per-bucket CSR + deg/dinv/offs
__global__ __launch_bounds__(256) void gemm1_final_kernel(
        const float* __restrict__ A, const unsigned short* __restrict__ Wt,
        unsigned short* __restrict__ Cb, int M, int ngemm,
        const unsigned* __restrict__ stage, const int* __restrict__ H,
        int* __restrict__ cnt, int* __restrict__ offs,
        float* __restrict__ dinv, int* __restrict__ csr) {
    __shared__ char smem[65536];
    const int tid = threadIdx.x;

    if ((int)blockIdx.x < ngemm) {
        // ---------- GEMM path ----------
        unsigned short* lds = (unsigned short*)smem;   // [hi 32KB][lo 32KB], pre-swizzled
        #pragma unroll
        for (int i = 0; i < 16; ++i) {
            int off = i * 4096 + tid * 16;
            *(uint4*)((char*)lds + off) = *(const uint4*)((const char*)Wt + off);
        }
        const int lane = tid & 63;
        const int wave = tid >> 6;
        const int c = lane & 15;
        const int g = lane >> 4;
        const int arow_i = blockIdx.x * 64 + wave * 16 + c;
        const bool inb = arow_i < M;
        const float* arow = A + (size_t)arow_i * D;

        bf16x8 ah[4], al[4];
        #pragma unroll
        for (int s = 0; s < 4; ++s) {
            int k0 = s * 32 + g * 8;
            float4 v0 = {0.f, 0.f, 0.f, 0.f}, v1 = {0.f, 0.f, 0.f, 0.f};
            if (inb) {
                v0 = *(const float4*)(arow + k0);
                v1 = *(const float4*)(arow + k0 + 4);
            }
            float av[8] = {v0.x, v0.y, v0.z, v0.w, v1.x, v1.y, v1.z, v1.w};
            #pragma unroll
            for (int j = 0; j < 8; ++j) {
                float f = av[j];
                unsigned short h = f2bf(f);
                unsigned short l = f2bf(f - bf2f(h));
                ah[s][j] = (short)h;
                al[s][j] = (short)l;
            }
        }
        __syncthreads();

        f32x4 acc[8];
        #pragma unroll
        for (int t = 0; t < 8; ++t) { f32x4 z = {0.f, 0.f, 0.f, 0.f}; acc[t] = z; }

        const int xmask = (lane & 7) << 4;
        #pragma unroll
        for (int s = 0; s < 4; ++s) {
            int lowk = (s * 64 + g * 16) ^ xmask;
            #pragma unroll
            for (int t = 0; t < 8; ++t) {
                int off = t * 4096 + c * 256 + lowk;
                bf16x8 bh = *(const bf16x8*)((const char*)lds + off);
                bf16x8 bl = *(const bf16x8*)((const char*)lds + 32768 + off);
                acc[t] = __builtin_amdgcn_mfma_f32_16x16x32_bf16(al[s], bh, acc[t], 0, 0, 0);
                acc[t] = __builtin_amdgcn_mfma_f32_16x16x32_bf16(ah[s], bl, acc[t], 0, 0, 0);
                acc[t] = __builtin_amdgcn_mfma_f32_16x16x32_bf16(ah[s], bh, acc[t], 0, 0, 0);
            }
        }

        const int r0 = blockIdx.x * 64 + wave * 16 + g * 4;
        #pragma unroll
        for (int t = 0; t < 8; ++t) {
            #pragma unroll
            for (int r = 0; r < 4; ++r) {
                int grow = r0 + r;
                if (grow < M) Cb[(size_t)grow * D + t * 16 + c] = f2bf(acc[t][r]);
            }
        }
    } else {
        // ---------- kfinal path ----------
        int* hist = (int*)smem;          // [256]
        int* sarr = hist + 256;          // [256]
        int* csum = sarr + 256;          // [256]
        const int t = tid;
        const int k = blockIdx.x - ngemm;
        // self-computed bucket base/size from H
        int tot = 0;
        if (t < NBUK)
            for (int b = 0; b < HB; ++b) tot += H[b * NBUK + t];
        csum[t] = (t < NBUK) ? tot : 0;
        sarr[t] = csum[t];
        __syncthreads();
        #pragma unroll
        for (int off = 1; off < 256; off <<= 1) {
            int add = (t >= off) ? sarr[t - off] : 0;
            __syncthreads();
            sarr[t] += add;
            __syncthreads();
        }
        const int base = sarr[k] - csum[k];
        const int size = csum[k];
        __syncthreads();

        hist[t] = 0;
        __syncthreads();
        for (int i = t; i < size; i += 256)
            atomicAdd(&hist[stage[base + i] >> 16], 1);
        __syncthreads();
        int deg = hist[t];
        sarr[t] = deg;
        __syncthreads();
        #pragma unroll
        for (int off = 1; off < 256; off <<= 1) {
            int add = (t >= off) ? sarr[t - off] : 0;
            __syncthreads();
            sarr[t] += add;
            __syncthreads();
        }
        int excl = sarr[t] - deg;
        int node = k * 256 + t;
        if (node < N_NODES) {
            cnt[node] = deg;
            offs[node] = base + excl;
            dinv[node] = rsqrtf((float)deg + 1.0f);
        }
        hist[t] = base + excl;   // reuse as cursor
        __syncthreads();
        for (int i = t; i < size; i += 256) {
            unsigned v = stage[base + i];
            int pos = atomicAdd(&hist[v >> 16], 1);
            csr[pos] = (int)(v & 0xffffu);
        }
    }
}

// ---------------- fused: gather layer-1 + gemm layer-2 ----------------
// Block = 64 consecutive nodes. Phase 1: 4 waves x 16 nodes aggregate
// out1[n] = relu(dinv[n]*sum + dinv[n]^2*self + b1) -> LDS f32 agg[64][132].
// Phase 2: hn2 = bf16(agg @ W2), B-frags streamed from L2-hot pre-swizzled Wt2.
__global__ __launch_bounds__(256) void gather_gemm2_kernel(
        const unsigned short* __restrict__ hnb, const float* __restrict__ dinv,
        const int* __restrict__ offs, const int* __restrict__ cnt,
        const int* __restrict__ csr, const float* __restrict__ bias1,
        const unsigned short* __restrict__ Wt2, unsigned short* __restrict__ hn2) {
    __shared__ float agg[64][132];   // padded stride: 2-way-max bank conflicts
    const int tid = threadIdx.x;
    const int lane = tid & 63;
    const int wave = tid >> 6;
    const int col = lane * 2;
    const float2 bv = *(const float2*)&bias1[col];

    // ---------- phase 1: aggregation ----------
    for (int nn = 0; nn < 16; ++nn) {
        const int n = blockIdx.x * 64 + wave * 16 + nn;
        float ox = 0.f, oy = 0.f;
        if (n < N_NODES) {
            const int beg = offs[n];
            const int m = cnt[n];
            float ax = 0.f, ay = 0.f;
            int i = 0;
            for (; i + 8 <= m; i += 8) {
                int sidx[8];
                #pragma unroll
                for (int j = 0; j < 8; ++j) sidx[j] = csr[beg + i + j];
                float w[8];
                unsigned v[8];
                #pragma unroll
                for (int j = 0; j < 8; ++j) {
                    w[j] = dinv[sidx[j]];
                    v[j] = *(const unsigned*)(hnb + (size_t)sidx[j] * D + col);
                }
                #pragma unroll
                for (int j = 0; j < 8; ++j) {
                    ax = fmaf(w[j], __uint_as_float(v[j] << 16), ax);
                    ay = fmaf(w[j], __uint_as_float(v[j] & 0xffff0000u), ay);
                }
            }
            for (; i + 4 <= m; i += 4) {
                int sidx[4];
                #pragma unroll
                for (int j = 0; j < 4; ++j) sidx[j] = csr[beg + i + j];
                #pragma unroll
                for (int j = 0; j < 4; ++j) {
                    float w = dinv[sidx[j]];
                    unsigned v = *(const unsigned*)(hnb + (size_t)sidx[j] * D + col);
                    ax = fmaf(w, __uint_as_float(v << 16), ax);
                    ay = fmaf(w, __uint_as_float(v & 0xffff0000u), ay);
                }
            }
            for (; i < m; ++i) {
                int s = csr[beg + i];
                float w = dinv[s];
                unsigned v = *(const unsigned*)(hnb + (size_t)s * D + col);
                ax = fmaf(w, __uint_as_float(v << 16), ax);
                ay = fmaf(w, __uint_as_float(v & 0xffff0000u), ay);
            }
            const float dn = dinv[n];
            const float dn2 = dn * dn;
            const unsigned hv = *(const unsigned*)(hnb + (size_t)n * D + col);
            ox = fmaxf(fmaf(dn, ax, fmaf(dn2, __uint_as_float(hv << 16), bv.x)), 0.f);
            oy = fmaxf(fmaf(dn, ay, fmaf(dn2, __uint_as_float(hv & 0xffff0000u), bv.y)), 0.f);
        }
        float2 o = {ox, oy};
        *(float2*)&agg[wave * 16 + nn][col] = o;
    }
    __syncthreads();

    // ---------- phase 2: MFMA split-bf16 GEMM, A from LDS, B from global (L2) ----------
    const int c = lane & 15;
    const int g = lane >> 4;
    const int arow = wave * 16 + c;

    bf16x8 ah[4], al[4];
    #pragma unroll
    for (int s = 0; s < 4; ++s) {
        int k0 = s * 32 + g * 8;
        float4 v0 = *(const float4*)&agg[arow][k0];
        float4 v1 = *(const float4*)&agg[arow][k0 + 4];
        float av[8] = {v0.x, v0.y, v0.z, v0.w, v1.x, v1.y, v1.z, v1.w};
        #pragma unroll
        for (int j = 0; j < 8; ++j) {
            float f = av[j];
            unsigned short h = f2bf(f);
            unsigned short l = f2bf(f - bf2f(h));
            ah[s][j] = (short)h;
            al[s][j] = (short)l;
        }
    }

    f32x4 acc[8];
    #pragma unroll
    for (int t = 0; t < 8; ++t) { f32x4 z = {0.f, 0.f, 0.f, 0.f}; acc[t] = z; }

    const int xmask = (lane & 7) << 4;
    #pragma unroll
    for (int s = 0; s < 4; ++s) {
        int lowk = (s * 64 + g * 16) ^ xmask;
        #pragma unroll
        for (int t = 0; t < 8; ++t) {
            int off = t * 4096 + c * 256 + lowk;
            bf16x8 bh = *(const bf16x8*)((const char*)Wt2 + off);
            bf16x8 bl = *(const bf16x8*)((const char*)Wt2 + 32768 + off);
            acc[t] = __builtin_amdgcn_mfma_f32_16x16x32_bf16(al[s], bh, acc[t], 0, 0, 0);
            acc[t] = __builtin_amdgcn_mfma_f32_16x16x32_bf16(ah[s], bl, acc[t], 0, 0, 0);
            acc[t] = __builtin_amdgcn_mfma_f32_16x16x32_bf16(ah[s], bh, acc[t], 0, 0, 0);
        }
    }

    const int r0 = blockIdx.x * 64 + wave * 16 + g * 4;
    #pragma unroll
    for (int t = 0; t < 8; ++t) {
        #pragma unroll
        for (int r = 0; r < 4; ++r) {
            int grow = r0 + r;
            if (grow < N_NODES) hn2[(size_t)grow * D + t * 16 + c] = f2bf(acc[t][r]);
        }
    }
}

// ---------------- CSR gather-aggregate (bf16 hn, per-edge dinv[src]) ----------------
// out[n][:] = dinv[n] * sum_s dinv[s]*hn[s][:] + dinv[n]^2*hn[n][:] + bias[:]
__global__ __launch_bounds__(256) void gather_kernel(const unsigned short* __restrict__ hnb,
                                                     const float* __restrict__ dinv,
                                                     const int* __restrict__ offs,
                                                     const int* __restrict__ cnt,
                                                     const int* __restrict__ csr,
                                                     const float* __restrict__ bias,
                                                     float* __restrict__ out) {
    const int wid = threadIdx.x >> 6;
    const int lane = threadIdx.x & 63;
    const int n = blockIdx.x * 4 + wid;
    if (n >= N_NODES) return;
    const int beg = offs[n];
    const int m = cnt[n];
    const int col = lane * 2;

    float ax = 0.f, ay = 0.f;
    int i = 0;
    for (; i + 8 <= m; i += 8) {
        int sidx[8];
        #pragma unroll
        for (int j = 0; j < 8; ++j) sidx[j] = csr[beg + i + j];
        float w[8];
        unsigned v[8];
        #pragma unroll
        for (int j = 0; j < 8; ++j) {
            w[j] = dinv[sidx[j]];
            v[j] = *(const unsigned*)(hnb + (size_t)sidx[j] * D + col);
        }
        #pragma unroll
        for (int j = 0; j < 8; ++j) {
            ax = fmaf(w[j], __uint_as_float(v[j] << 16), ax);
            ay = fmaf(w[j], __uint_as_float(v[j] & 0xffff0000u), ay);
        }
    }
    for (; i + 4 <= m; i += 4) {
        int sidx[4];
        #pragma unroll
        for (int j = 0; j < 4; ++j) sidx[j] = csr[beg + i + j];
        #pragma unroll
        for (int j = 0; j < 4; ++j) {
            float w = dinv[sidx[j]];
            unsigned v = *(const unsigned*)(hnb + (size_t)sidx[j] * D + col);
            ax = fmaf(w, __uint_as_float(v << 16), ax);
            ay = fmaf(w, __uint_as_float(v & 0xffff0000u), ay);
        }
    }
    for (; i < m; ++i) {
        int s = csr[beg + i];
        float w = dinv[s];
        unsigned v = *(const unsigned*)(hnb + (size_t)s * D + col);
        ax = fmaf(w, __uint_as_float(v << 16), ax);
        ay = fmaf(w, __uint_as_float(v & 0xffff0000u), ay);
    }
    float dn = dinv[n];
    float dn2 = dn * dn;
    unsigned hv = *(const unsigned*)(hnb + (size_t)n * D + col);
    float2 bv = *(const float2*)&bias[col];
    float ox = fmaf(dn, ax, fmaf(dn2, __uint_as_float(hv << 16), bv.x));
    float oy = fmaf(dn, ay, fmaf(dn2, __uint_as_float(hv & 0xffff0000u), bv.y));
    float2 o = {ox, oy};
    *(float2*)&out[(size_t)n * D + col] = o;
}

extern "C" void kernel_launch(void* const* d_in, const int* in_sizes, int n_in,
                              void* d_out, int out_size, void* d_ws, size_t ws_size,
                              hipStream_t stream) {
    const float* x  = (const float*)d_in[0];
    const int*   ei = (const int*)d_in[1];
    const float* W1 = (const float*)d_in[2];
    const float* b1 = (const float*)d_in[3];
    const float* W2 = (const float*)d_in[4];
    const float* b2 = (const float*)d_in[5];
    float* out = (float*)d_out;

    const int* src = ei;
    const int* dst = ei + N_EDGES;

    // workspace layout (int units unless noted)
    int* wsi = (int*)d_ws;
    int*      cnt   = wsi;                        // [50176]
    int*      offs  = cnt + 50176;                // [50176]
    float*    dinv  = (float*)(offs + 50176);     // [50176]
    int*      H     = (int*)(dinv + 50176);       // [HB*NBUK = 25088]
    unsigned* stage = (unsigned*)(H + 25088);     // [800000]
    int*      csr   = (int*)(stage + 800000);     // [800000]
    unsigned short* Wt  = (unsigned short*)(csr + 800000);  // [2*32768]
    unsigned short* hn  = Wt + 65536;                       // [N*128] bf16
    unsigned short* hn2 = hn + (size_t)N_NODES * D + 64;    // [N*128] bf16

    const int Bt = 256;
    const int gemm_grid = (N_NODES + 63) / 64;    // 782
    const int gather_grid = (N_NODES + 3) / 4;

    // prepw (blocks 0..127) + bucket histogram (blocks 128..255)
    prep_hist_kernel<<<256, Bt, 0, stream>>>(W1, W2, Wt, dst, H);
    // stage with self-computed bases (kscan eliminated)
    kstage_kernel<<<HB, Bt, 0, stream>>>(src, dst, H, stage);

    // gemm1 (blocks 0..781: hn = bf16(x @ W1)) + kfinal (blocks 782..977: CSR+dinv)
    gemm1_final_kernel<<<gemm_grid + NBUK, Bt, 0, stream>>>(
        x, Wt, hn, N_NODES, gemm_grid,
        stage, H, cnt, offs, dinv, csr);

    // fused: layer-1 aggregation (+b1, relu) + layer-2 GEMM -> hn2
    gather_gemm2_kernel<<<gemm_grid, Bt, 0, stream>>>(
        hn, dinv, offs, cnt, csr, b1, Wt + 32768, hn2);

    // layer-2 aggregation (+b2) -> out (f32)
    gather_kernel<<<gather_grid, Bt, 0, stream>>>(hn2, dinv, offs, cnt, csr, b2, out);
}

// Round 15
// 215.318 us; speedup vs baseline: 1.0642x; 1.0642x over previous
//
#include <hip/hip_runtime.h>

#define N_NODES 50000
#define N_EDGES 800000
#define D 128
#define NBUK 196     // buckets of 256 nodes (dst>>8)
#define HB 128       // histogram/staging blocks
#define EPB 6250     // edges per block: 128*6250 = 800000 exactly

typedef __attribute__((ext_vector_type(8))) short bf16x8;
typedef __attribute__((ext_vector_type(4))) float f32x4;

__device__ inline unsigned short f2bf(float f) {
    unsigned u = __float_as_uint(f);
    u += 0x7fffu + ((u >> 16) & 1u);   // round-to-nearest-even
    return (unsigned short)(u >> 16);
}
__device__ inline float bf2f(unsigned short h) {
    return __uint_as_float((unsigned)h << 16);
}

// ---------------- merged: W prep (blocks 0..127) + bucket histogram (blocks 128..255) ----
__global__ __launch_bounds__(256) void prep_hist_kernel(const float* __restrict__ W1,
                                                        const float* __restrict__ W2,
                                                        unsigned short* __restrict__ Wt,
                                                        const int* __restrict__ dst,
                                                        int* __restrict__ H) {
    __shared__ int hist[NBUK];
    const int b = blockIdx.x;
    const int t = threadIdx.x;
    if (b < 128) {
        // W prep: transpose + split-bf16 + XOR swizzle
        int tid = b * 256 + t;          // 0..32767
        int a = tid >> 14;
        int idx = tid & 16383;
        const float* W = a ? W2 : W1;
        float w = W[idx];
        unsigned short hi = f2bf(w);
        unsigned short lo = f2bf(w - bf2f(hi));
        int k = idx >> 7, col = idx & 127;
        int byte = (col * 128 + k) * 2;
        int swz = byte ^ (((byte >> 8) & 7) << 4);
        unsigned short* base = Wt + a * 32768;
        *(unsigned short*)((char*)base + swz) = hi;
        *(unsigned short*)((char*)(base + 16384) + swz) = lo;
    } else {
        // per-block bucket histogram (no global atomics)
        const int blk = b - 128;
        if (t < NBUK) hist[t] = 0;
        __syncthreads();
        const int e0 = blk * EPB;
        for (int i = t; i < EPB; i += 256)
            atomicAdd(&hist[dst[e0 + i] >> 8], 1);
        __syncthreads();
        if (t < NBUK) H[blk * NBUK + t] = hist[t];
    }
}

// ---------------- stage: self-computed bases + scatter into block-exclusive ranges -----
__global__ __launch_bounds__(256) void kstage_kernel(const int* __restrict__ src,
                                                     const int* __restrict__ dst,
                                                     const int* __restrict__ H,
                                                     unsigned* __restrict__ stage) {
    __shared__ int cur[256];
    __shared__ int sarr[256];
    const int t = threadIdx.x;
    const int myb = blockIdx.x;
    // column sums + my-block prefix from H (L2-hot, 100 KB)
    int tot = 0, pre = 0;
    if (t < NBUK) {
        for (int b = 0; b < HB; ++b) {
            int h = H[b * NBUK + t];
            tot += h;
            if (b < myb) pre += h;
        }
    }
    sarr[t] = (t < NBUK) ? tot : 0;
    __syncthreads();
    #pragma unroll
    for (int off = 1; off < 256; off <<= 1) {
        int add = (t >= off) ? sarr[t - off] : 0;
        __syncthreads();
        sarr[t] += add;
        __syncthreads();
    }
    if (t < NBUK) cur[t] = (sarr[t] - tot) + pre;   // bucket base + my prefix
    __syncthreads();
    const int e0 = myb * EPB;
    for (int i = t; i < EPB; i += 256) {
        int d = dst[e0 + i];
        int s = src[e0 + i];
        int pos = atomicAdd(&cur[d >> 8], 1);
        stage[pos] = (unsigned)s | ((unsigned)(d & 255) << 16);
    }
}

// ---------------- merged: gemm1 (blocks 0..781) + kfinal (blocks 782..977) -------------
// gemm: Cb[row][col] (bf16) = A[row][:] @ W  via split-bf16 MFMA (3 mfma/tile)
// kfinal: self-computed bucket base/size from H; per-bucket CSR + deg/dinv/offs
__global__ __launch_bounds__(256) void gemm1_final_kernel(
        const float* __restrict__ A, const unsigned short* __restrict__ Wt,
        unsigned short* __restrict__ Cb, int M, int ngemm,
        const unsigned* __restrict__ stage, const int* __restrict__ H,
        int* __restrict__ cnt, int* __restrict__ offs,
        float* __restrict__ dinv, int* __restrict__ csr) {
    __shared__ char smem[65536];
    const int tid = threadIdx.x;

    if ((int)blockIdx.x < ngemm) {
        // ---------- GEMM path ----------
        unsigned short* lds = (unsigned short*)smem;   // [hi 32KB][lo 32KB], pre-swizzled
        #pragma unroll
        for (int i = 0; i < 16; ++i) {
            int off = i * 4096 + tid * 16;
            *(uint4*)((char*)lds + off) = *(const uint4*)((const char*)Wt + off);
        }
        const int lane = tid & 63;
        const int wave = tid >> 6;
        const int c = lane & 15;
        const int g = lane >> 4;
        const int arow_i = blockIdx.x * 64 + wave * 16 + c;
        const bool inb = arow_i < M;
        const float* arow = A + (size_t)arow_i * D;

        bf16x8 ah[4], al[4];
        #pragma unroll
        for (int s = 0; s < 4; ++s) {
            int k0 = s * 32 + g * 8;
            float4 v0 = {0.f, 0.f, 0.f, 0.f}, v1 = {0.f, 0.f, 0.f, 0.f};
            if (inb) {
                v0 = *(const float4*)(arow + k0);
                v1 = *(const float4*)(arow + k0 + 4);
            }
            float av[8] = {v0.x, v0.y, v0.z, v0.w, v1.x, v1.y, v1.z, v1.w};
            #pragma unroll
            for (int j = 0; j < 8; ++j) {
                float f = av[j];
                unsigned short h = f2bf(f);
                unsigned short l = f2bf(f - bf2f(h));
                ah[s][j] = (short)h;
                al[s][j] = (short)l;
            }
        }
        __syncthreads();

        f32x4 acc[8];
        #pragma unroll
        for (int t = 0; t < 8; ++t) { f32x4 z = {0.f, 0.f, 0.f, 0.f}; acc[t] = z; }

        const int xmask = (lane & 7) << 4;
        #pragma unroll
        for (int s = 0; s < 4; ++s) {
            int lowk = (s * 64 + g * 16) ^ xmask;
            #pragma unroll
            for (int t = 0; t < 8; ++t) {
                int off = t * 4096 + c * 256 + lowk;
                bf16x8 bh = *(const bf16x8*)((const char*)lds + off);
                bf16x8 bl = *(const bf16x8*)((const char*)lds + 32768 + off);
                acc[t] = __builtin_amdgcn_mfma_f32_16x16x32_bf16(al[s], bh, acc[t], 0, 0, 0);
                acc[t] = __builtin_amdgcn_mfma_f32_16x16x32_bf16(ah[s], bl, acc[t], 0, 0, 0);
                acc[t] = __builtin_amdgcn_mfma_f32_16x16x32_bf16(ah[s], bh, acc[t], 0, 0, 0);
            }
        }

        const int r0 = blockIdx.x * 64 + wave * 16 + g * 4;
        #pragma unroll
        for (int t = 0; t < 8; ++t) {
            #pragma unroll
            for (int r = 0; r < 4; ++r) {
                int grow = r0 + r;
                if (grow < M) Cb[(size_t)grow * D + t * 16 + c] = f2bf(acc[t][r]);
            }
        }
    } else {
        // ---------- kfinal path ----------
        int* hist = (int*)smem;          // [256]
        int* sarr = hist + 256;          // [256]
        int* csum = sarr + 256;          // [256]
        const int t = tid;
        const int k = blockIdx.x - ngemm;
        // self-computed bucket base/size from H
        int tot = 0;
        if (t < NBUK)
            for (int b = 0; b < HB; ++b) tot += H[b * NBUK + t];
        csum[t] = (t < NBUK) ? tot : 0;
        sarr[t] = csum[t];
        __syncthreads();
        #pragma unroll
        for (int off = 1; off < 256; off <<= 1) {
            int add = (t >= off) ? sarr[t - off] : 0;
            __syncthreads();
            sarr[t] += add;
            __syncthreads();
        }
        const int base = sarr[k] - csum[k];
        const int size = csum[k];
        __syncthreads();

        hist[t] = 0;
        __syncthreads();
        for (int i = t; i < size; i += 256)
            atomicAdd(&hist[stage[base + i] >> 16], 1);
        __syncthreads();
        int deg = hist[t];
        sarr[t] = deg;
        __syncthreads();
        #pragma unroll
        for (int off = 1; off < 256; off <<= 1) {
            int add = (t >= off) ? sarr[t - off] : 0;
            __syncthreads();
            sarr[t] += add;
            __syncthreads();
        }
        int excl = sarr[t] - deg;
        int node = k * 256 + t;
        if (node < N_NODES) {
            cnt[node] = deg;
            offs[node] = base + excl;
            dinv[node] = rsqrtf((float)deg + 1.0f);
        }
        hist[t] = base + excl;   // reuse as cursor
        __syncthreads();
        for (int i = t; i < size; i += 256) {
            unsigned v = stage[base + i];
            int pos = atomicAdd(&hist[v >> 16], 1);
            csr[pos] = (int)(v & 0xffffu);
        }
    }
}

// ---------------- standalone split-bf16 MFMA GEMM (layer 2, relu on load) ---------------
__global__ __launch_bounds__(256) void mfma_gemm_relu_kernel(const float* __restrict__ A,
                                                             const unsigned short* __restrict__ Wt,
                                                             unsigned short* __restrict__ Cb,
                                                             int M) {
    __shared__ unsigned short lds[32768];
    const int tid = threadIdx.x;
    #pragma unroll
    for (int i = 0; i < 16; ++i) {
        int off = i * 4096 + tid * 16;
        *(uint4*)((char*)lds + off) = *(const uint4*)((const char*)Wt + off);
    }
    const int lane = tid & 63;
    const int wave = tid >> 6;
    const int c = lane & 15;
    const int g = lane >> 4;
    const int arow_i = blockIdx.x * 64 + wave * 16 + c;
    const bool inb = arow_i < M;
    const float* arow = A + (size_t)arow_i * D;

    bf16x8 ah[4], al[4];
    #pragma unroll
    for (int s = 0; s < 4; ++s) {
        int k0 = s * 32 + g * 8;
        float4 v0 = {0.f, 0.f, 0.f, 0.f}, v1 = {0.f, 0.f, 0.f, 0.f};
        if (inb) {
            v0 = *(const float4*)(arow + k0);
            v1 = *(const float4*)(arow + k0 + 4);
        }
        float av[8] = {v0.x, v0.y, v0.z, v0.w, v1.x, v1.y, v1.z, v1.w};
        #pragma unroll
        for (int j = 0; j < 8; ++j) {
            float f = fmaxf(av[j], 0.f);
            unsigned short h = f2bf(f);
            unsigned short l = f2bf(f - bf2f(h));
            ah[s][j] = (short)h;
            al[s][j] = (short)l;
        }
    }
    __syncthreads();

    f32x4 acc[8];
    #pragma unroll
    for (int t = 0; t < 8; ++t) { f32x4 z = {0.f, 0.f, 0.f, 0.f}; acc[t] = z; }

    const int xmask = (lane & 7) << 4;
    #pragma unroll
    for (int s = 0; s < 4; ++s) {
        int lowk = (s * 64 + g * 16) ^ xmask;
        #pragma unroll
        for (int t = 0; t < 8; ++t) {
            int off = t * 4096 + c * 256 + lowk;
            bf16x8 bh = *(const bf16x8*)((const char*)lds + off);
            bf16x8 bl = *(const bf16x8*)((const char*)lds + 32768 + off);
            acc[t] = __builtin_amdgcn_mfma_f32_16x16x32_bf16(al[s], bh, acc[t], 0, 0, 0);
            acc[t] = __builtin_amdgcn_mfma_f32_16x16x32_bf16(ah[s], bl, acc[t], 0, 0, 0);
            acc[t] = __builtin_amdgcn_mfma_f32_16x16x32_bf16(ah[s], bh, acc[t], 0, 0, 0);
        }
    }

    const int r0 = blockIdx.x * 64 + wave * 16 + g * 4;
    #pragma unroll
    for (int t = 0; t < 8; ++t) {
        #pragma unroll
        for (int r = 0; r < 4; ++r) {
            int grow = r0 + r;
            if (grow < M) Cb[(size_t)grow * D + t * 16 + c] = f2bf(acc[t][r]);
        }
    }
}

// ---------------- CSR gather-aggregate (bf16 hn, per-edge dinv[src]) ----------------
// out[n][:] = dinv[n] * sum_s dinv[s]*hn[s][:] + dinv[n]^2*hn[n][:] + bias[:]
__global__ __launch_bounds__(256) void gather_kernel(const unsigned short* __restrict__ hnb,
                                                     const float* __restrict__ dinv,
                                                     const int* __restrict__ offs,
                                                     const int* __restrict__ cnt,
                                                     const int* __restrict__ csr,
                                                     const float* __restrict__ bias,
                                                     float* __restrict__ out) {
    const int wid = threadIdx.x >> 6;
    const int lane = threadIdx.x & 63;
    const int n = blockIdx.x * 4 + wid;
    if (n >= N_NODES) return;
    const int beg = offs[n];
    const int m = cnt[n];
    const int col = lane * 2;

    float ax = 0.f, ay = 0.f;
    int i = 0;
    for (; i + 8 <= m; i += 8) {
        int sidx[8];
        #pragma unroll
        for (int j = 0; j < 8; ++j) sidx[j] = csr[beg + i + j];
        float w[8];
        unsigned v[8];
        #pragma unroll
        for (int j = 0; j < 8; ++j) {
            w[j] = dinv[sidx[j]];
            v[j] = *(const unsigned*)(hnb + (size_t)sidx[j] * D + col);
        }
        #pragma unroll
        for (int j = 0; j < 8; ++j) {
            ax = fmaf(w[j], __uint_as_float(v[j] << 16), ax);
            ay = fmaf(w[j], __uint_as_float(v[j] & 0xffff0000u), ay);
        }
    }
    for (; i + 4 <= m; i += 4) {
        int sidx[4];
        #pragma unroll
        for (int j = 0; j < 4; ++j) sidx[j] = csr[beg + i + j];
        #pragma unroll
        for (int j = 0; j < 4; ++j) {
            float w = dinv[sidx[j]];
            unsigned v = *(const unsigned*)(hnb + (size_t)sidx[j] * D + col);
            ax = fmaf(w, __uint_as_float(v << 16), ax);
            ay = fmaf(w, __uint_as_float(v & 0xffff0000u), ay);
        }
    }
    for (; i < m; ++i) {
        int s = csr[beg + i];
        float w = dinv[s];
        unsigned v = *(const unsigned*)(hnb + (size_t)s * D + col);
        ax = fmaf(w, __uint_as_float(v << 16), ax);
        ay = fmaf(w, __uint_as_float(v & 0xffff0000u), ay);
    }
    float dn = dinv[n];
    float dn2 = dn * dn;
    unsigned hv = *(const unsigned*)(hnb + (size_t)n * D + col);
    float2 bv = *(const float2*)&bias[col];
    float ox = fmaf(dn, ax, fmaf(dn2, __uint_as_float(hv << 16), bv.x));
    float oy = fmaf(dn, ay, fmaf(dn2, __uint_as_float(hv & 0xffff0000u), bv.y));
    float2 o = {ox, oy};
    *(float2*)&out[(size_t)n * D + col] = o;
}

extern "C" void kernel_launch(void* const* d_in, const int* in_sizes, int n_in,
                              void* d_out, int out_size, void* d_ws, size_t ws_size,
                              hipStream_t stream) {
    const float* x  = (const float*)d_in[0];
    const int*   ei = (const int*)d_in[1];
    const float* W1 = (const float*)d_in[2];
    const float* b1 = (const float*)d_in[3];
    const float* W2 = (const float*)d_in[4];
    const float* b2 = (const float*)d_in[5];
    float* out = (float*)d_out;

    const int* src = ei;
    const int* dst = ei + N_EDGES;

    // workspace layout (int units unless noted)
    int* wsi = (int*)d_ws;
    int*      cnt   = wsi;                        // [50176]
    int*      offs  = cnt + 50176;                // [50176]
    float*    dinv  = (float*)(offs + 50176);     // [50176]
    int*      H     = (int*)(dinv + 50176);       // [HB*NBUK = 25088]
    unsigned* stage = (unsigned*)(H + 25088);     // [800000]
    int*      csr   = (int*)(stage + 800000);     // [800000]
    unsigned short* Wt = (unsigned short*)(csr + 800000);   // [2*32768]
    unsigned short* hn = Wt + 65536;                        // [N*128] bf16
    float* agg1 = (float*)(hn + (size_t)N_NODES * D + 64);  // [N*128] f32

    const int Bt = 256;
    const int gemm_grid = (N_NODES + 63) / 64;    // 782
    const int gather_grid = (N_NODES + 3) / 4;

    // prepw (blocks 0..127) + bucket histogram (blocks 128..255)
    prep_hist_kernel<<<256, Bt, 0, stream>>>(W1, W2, Wt, dst, H);
    // stage with self-computed bases (no kscan)
    kstage_kernel<<<HB, Bt, 0, stream>>>(src, dst, H, stage);

    // gemm1 (blocks 0..781: hn = bf16(x @ W1)) + kfinal (blocks 782..977: CSR+dinv)
    gemm1_final_kernel<<<gemm_grid + NBUK, Bt, 0, stream>>>(
        x, Wt, hn, N_NODES, gemm_grid,
        stage, H, cnt, offs, dinv, csr);

    // layer-1 aggregation (+b1) -> agg1 (f32)
    gather_kernel<<<gather_grid, Bt, 0, stream>>>(hn, dinv, offs, cnt, csr, b1, agg1);

    // layer 2: hn = bf16(relu(agg1) @ W2)
    mfma_gemm_relu_kernel<<<gemm_grid, Bt, 0, stream>>>(agg1, Wt + 32768, hn, N_NODES);

    // layer-2 aggregation (+b2) -> out (f32)
    gather_kernel<<<gather_grid, Bt, 0, stream>>>(hn, dinv, offs, cnt, csr, b2, out);
}